// Round 1
// baseline (554.536 us; speedup 1.0000x reference)
//
#include <hip/hip_runtime.h>

#define NMAT 2048
#define KATTR 64
#define CAP 128
#define NITER 10

typedef unsigned short ushort4v __attribute__((ext_vector_type(4)));

__device__ __forceinline__ unsigned short f2bf(float f) {
  unsigned u = __float_as_uint(f);
  return (unsigned short)((u + 0x7fff + ((u >> 16) & 1)) >> 16);
}
__device__ __forceinline__ float bf2f(unsigned short b) {
  return __uint_as_float((unsigned)b << 16);
}
// bf16 pair in one uint (little-endian: low half = first value)
__device__ __forceinline__ float bflo(unsigned v) {
  return __uint_as_float(v << 16);
}
__device__ __forceinline__ float bfhi(unsigned v) {
  return __uint_as_float(v & 0xffff0000u);
}

// add 8 bf16 (one uint4) into acc[0..7]
__device__ __forceinline__ void addv8(float* a, uint4 v) {
  a[0] += bflo(v.x); a[1] += bfhi(v.x);
  a[2] += bflo(v.y); a[3] += bfhi(v.y);
  a[4] += bflo(v.z); a[5] += bfhi(v.z);
  a[6] += bflo(v.w); a[7] += bfhi(v.w);
}
__device__ __forceinline__ void addf8(float* a, float4 x, float4 y) {
  a[0] += x.x; a[1] += x.y; a[2] += x.z; a[3] += x.w;
  a[4] += y.x; a[5] += y.y; a[6] += y.z; a[7] += y.w;
}

// --------------------------------------------------------------------------
// Build padded adjacency (ELL) for pattern(A); B == (A!=0), symmetric.
// idxT4 (for Phase B): 4 edges per group, group g of column r stored at
// idxT4[g*NMAT*4 + r*4 + (p&3)]  -> one 8B read per 4 edges, lane-contiguous.
// --------------------------------------------------------------------------
__global__ __launch_bounds__(256) void k_build(
    const float* __restrict__ A, unsigned short* __restrict__ idx,
    unsigned short* __restrict__ idxT4, int* __restrict__ cnt) {
  __shared__ int lcnt;
  int r = blockIdx.x;
  if (threadIdx.x == 0) lcnt = 0;
  __syncthreads();
  const float* row = A + (size_t)r * NMAT;
  for (int c = threadIdx.x; c < NMAT; c += 256) {
    if (row[c] != 0.0f) {
      int p = atomicAdd(&lcnt, 1);
      if (p < CAP) {
        idx[r * CAP + p] = (unsigned short)c;
        if (idxT4)
          idxT4[(size_t)(p >> 2) * (NMAT * 4) + r * 4 + (p & 3)] =
              (unsigned short)c;
      }
    }
  }
  __syncthreads();
  if (threadIdx.x == 0) cnt[r] = lcnt < CAP ? lcnt : CAP;
}

__global__ __launch_bounds__(256) void k_norm(const float* __restrict__ Nin,
                                              float* __restrict__ Nout) {
  int row = blockIdx.x * 4 + (threadIdx.x >> 6);
  int lane = threadIdx.x & 63;
  float v = Nin[(size_t)row * KATTR + lane];
  float ss = v * v;
#pragma unroll
  for (int o = 32; o > 0; o >>= 1) ss += __shfl_xor(ss, o);
  float nrm = sqrtf(ss);
  Nout[(size_t)row * KATTR + lane] = (nrm > 0.f) ? v / nrm : 0.f;
}

__global__ void k_gatherN(const unsigned short* __restrict__ idx,
                          const int* __restrict__ cnt,
                          const float* __restrict__ Nn,
                          float* __restrict__ C) {
  int i = blockIdx.x;
  int lane = threadIdx.x;  // blockDim = 64
  int nn = cnt[i];
  const unsigned short* ip = idx + i * CAP;
  float acc = 0.f;
  for (int t = 0; t < nn; ++t) {
    int k = ip[t];
    acc += Nn[(size_t)k * KATTR + lane];
  }
  C[(size_t)i * KATTR + lane] = acc;
}

__global__ __launch_bounds__(256) void k_transpose(const float* __restrict__ H,
                                                   float* __restrict__ Ht) {
  __shared__ float tile[64][65];
  int j0 = blockIdx.x * 64;
  int i0 = blockIdx.y * 64;
  int c = threadIdx.x & 63;
  int r0 = threadIdx.x >> 6;
  for (int r = r0; r < 64; r += 4)
    tile[r][c] = H[(size_t)(j0 + r) * NMAT + i0 + c];
  __syncthreads();
  for (int r = r0; r < 64; r += 4)
    Ht[(size_t)(i0 + r) * NMAT + j0 + c] = tile[c][r];
}

// --------------------------------------------------------------------------
// q = Nm>0&dm>0 ? Nm*rsqrt(Nm*dm) : 0.
// Also: M0gather = bf16(q*Ht), Q2 = alpha*q^2, M0base = bf16((1-a)*q*Ht)
// --------------------------------------------------------------------------
__global__ __launch_bounds__(256) void k_q(
    const float* __restrict__ N1n, const float* __restrict__ C1,
    const float* __restrict__ N2n, const float* __restrict__ C2,
    const float* __restrict__ Ht, float* __restrict__ q,
    float* __restrict__ Q2, unsigned short* __restrict__ M,
    unsigned short* __restrict__ M0base) {
  __shared__ float sA[64][68];
  __shared__ float sB[64][68];
  int i0 = blockIdx.y * 64, j0 = blockIdx.x * 64;
  int c = threadIdx.x & 63, r0 = threadIdx.x >> 6;
  int tx = threadIdx.x & 15, ty = threadIdx.x >> 4;
  const float alpha = 0.82f;

  float nmv[4][4] = {};
  float dmv[4][4] = {};

  for (int r = r0; r < 64; r += 4) {
    sA[c][r] = N1n[(size_t)(i0 + r) * KATTR + c];
    sB[c][r] = N2n[(size_t)(j0 + r) * KATTR + c];
  }
  __syncthreads();
#pragma unroll 4
  for (int k = 0; k < 64; ++k) {
    float4 a = *(const float4*)&sA[k][ty * 4];
    float4 b = *(const float4*)&sB[k][tx * 4];
    float av[4] = {a.x, a.y, a.z, a.w};
    float bv[4] = {b.x, b.y, b.z, b.w};
#pragma unroll
    for (int ii = 0; ii < 4; ++ii)
#pragma unroll
      for (int jj = 0; jj < 4; ++jj)
        nmv[ii][jj] = fmaf(av[ii], bv[jj], nmv[ii][jj]);
  }
  __syncthreads();
  for (int r = r0; r < 64; r += 4) {
    sA[c][r] = C1[(size_t)(i0 + r) * KATTR + c];
    sB[c][r] = C2[(size_t)(j0 + r) * KATTR + c];
  }
  __syncthreads();
#pragma unroll 4
  for (int k = 0; k < 64; ++k) {
    float4 a = *(const float4*)&sA[k][ty * 4];
    float4 b = *(const float4*)&sB[k][tx * 4];
    float av[4] = {a.x, a.y, a.z, a.w};
    float bv[4] = {b.x, b.y, b.z, b.w};
#pragma unroll
    for (int ii = 0; ii < 4; ++ii)
#pragma unroll
      for (int jj = 0; jj < 4; ++jj)
        dmv[ii][jj] = fmaf(av[ii], bv[jj], dmv[ii][jj]);
  }

#pragma unroll
  for (int ii = 0; ii < 4; ++ii) {
    int i = i0 + ty * 4 + ii;
    size_t base = (size_t)i * NMAT + j0 + tx * 4;
    float4 hv = *(const float4*)&Ht[base];
    float hvv[4] = {hv.x, hv.y, hv.z, hv.w};
    float qv[4], q2v[4];
    ushort4v mv, m0v;
#pragma unroll
    for (int jj = 0; jj < 4; ++jj) {
      float nmx = nmv[ii][jj];
      float D = nmx * dmv[ii][jj];
      float qq = (D > 0.f) ? nmx * rsqrtf(D) : 0.f;
      qv[jj] = qq;
      q2v[jj] = alpha * qq * qq;
      float m0 = qq * hvv[jj];
      mv[jj] = f2bf(m0);
      m0v[jj] = f2bf((1.0f - alpha) * m0);
    }
    *(float4*)&q[base] = make_float4(qv[0], qv[1], qv[2], qv[3]);
    *(float4*)&Q2[base] = make_float4(q2v[0], q2v[1], q2v[2], q2v[3]);
    *(ushort4v*)&M[base] = mv;
    *(ushort4v*)&M0base[base] = m0v;
  }
}

// --------------------------------------------------------------------------
// One full iteration, fused (v4). Grid 1024 x 256 threads (4 waves/block,
// 4 blocks/CU). Evidence from v3 counters: fp32-gather iteration moved 2x
// the bytes in the same time at the same request count -> Phase A is
// request-rate bound, not byte bound. So: 2 rows/block, 8 cols/thread,
// one uint4 (16B) per edge -> 4x fewer gather requests. 4 independent
// blocks/CU provide A/B phase stagger; T1 stored bf16-packed (both rows in
// one uint) -> Phase B = 1 conflict-free random ds_read_b32 per edge.
// Edge lists for Phase B packed 4/group (idx2T4) -> 4x fewer index reads.
// --------------------------------------------------------------------------
__global__ __launch_bounds__(256, 4) void k_iter(
    const unsigned short* __restrict__ idx1, const int* __restrict__ cnt1,
    const unsigned short* __restrict__ idx2T4, const int* __restrict__ cnt2,
    const unsigned short* __restrict__ Min, const float* __restrict__ MinF,
    const float* __restrict__ Q2, const unsigned short* __restrict__ M0base,
    const float* __restrict__ q, const float* __restrict__ Ht,
    unsigned short* __restrict__ Mout, float* __restrict__ MoutF,
    float* __restrict__ sout, int in32, int out32, int last) {
  __shared__ float2 ldsF[NMAT + 8];  // fp32 path: float2{row0,row1}
  unsigned* ldsU = (unsigned*)ldsF;  // bf16 path: packed pair per column
  const int GS = NMAT * 4;           // idx2T4 group stride (ushorts)
  int i0 = blockIdx.x * 2;
  int tid = threadIdx.x;  // 0..255
  int c0 = tid * 8;       // this thread's 8 columns

  // ---- Phase A: row gathers (16B per lane per edge) ----
  float acc[2][8] = {};
#pragma unroll
  for (int r = 0; r < 2; ++r) {
    int nn = cnt1[i0 + r];
    const unsigned short* ip = idx1 + (i0 + r) * CAP;
    float* a = acc[r];
    int t = 0;
    if (in32) {
      const float* Mb = MinF;
      for (; t + 4 <= nn; t += 4) {
        uint2 pk = *(const uint2*)(ip + t);
        int k0 = pk.x & 0xffff, k1 = pk.x >> 16;
        int k2 = pk.y & 0xffff, k3 = pk.y >> 16;
        const float* p0 = Mb + (size_t)k0 * NMAT + c0;
        const float* p1 = Mb + (size_t)k1 * NMAT + c0;
        const float* p2 = Mb + (size_t)k2 * NMAT + c0;
        const float* p3 = Mb + (size_t)k3 * NMAT + c0;
        float4 x0 = *(const float4*)p0, y0 = *(const float4*)(p0 + 4);
        float4 x1 = *(const float4*)p1, y1 = *(const float4*)(p1 + 4);
        float4 x2 = *(const float4*)p2, y2 = *(const float4*)(p2 + 4);
        float4 x3 = *(const float4*)p3, y3 = *(const float4*)(p3 + 4);
        addf8(a, x0, y0); addf8(a, x1, y1);
        addf8(a, x2, y2); addf8(a, x3, y3);
      }
      for (; t < nn; ++t) {
        const float* p0 = Mb + (size_t)ip[t] * NMAT + c0;
        addf8(a, *(const float4*)p0, *(const float4*)(p0 + 4));
      }
    } else {
      for (; t + 8 <= nn; t += 8) {
        uint4 pk = *(const uint4*)(ip + t);  // 16B aligned (t%8==0, CAP=128)
        int k0 = pk.x & 0xffff, k1 = pk.x >> 16;
        int k2 = pk.y & 0xffff, k3 = pk.y >> 16;
        int k4 = pk.z & 0xffff, k5 = pk.z >> 16;
        int k6 = pk.w & 0xffff, k7 = pk.w >> 16;
        uint4 v0 = *(const uint4*)(Min + (size_t)k0 * NMAT + c0);
        uint4 v1 = *(const uint4*)(Min + (size_t)k1 * NMAT + c0);
        uint4 v2 = *(const uint4*)(Min + (size_t)k2 * NMAT + c0);
        uint4 v3 = *(const uint4*)(Min + (size_t)k3 * NMAT + c0);
        uint4 v4 = *(const uint4*)(Min + (size_t)k4 * NMAT + c0);
        uint4 v5 = *(const uint4*)(Min + (size_t)k5 * NMAT + c0);
        uint4 v6 = *(const uint4*)(Min + (size_t)k6 * NMAT + c0);
        uint4 v7 = *(const uint4*)(Min + (size_t)k7 * NMAT + c0);
        addv8(a, v0); addv8(a, v1); addv8(a, v2); addv8(a, v3);
        addv8(a, v4); addv8(a, v5); addv8(a, v6); addv8(a, v7);
      }
      for (; t + 4 <= nn; t += 4) {
        uint2 pk = *(const uint2*)(ip + t);
        int k0 = pk.x & 0xffff, k1 = pk.x >> 16;
        int k2 = pk.y & 0xffff, k3 = pk.y >> 16;
        uint4 v0 = *(const uint4*)(Min + (size_t)k0 * NMAT + c0);
        uint4 v1 = *(const uint4*)(Min + (size_t)k1 * NMAT + c0);
        uint4 v2 = *(const uint4*)(Min + (size_t)k2 * NMAT + c0);
        uint4 v3 = *(const uint4*)(Min + (size_t)k3 * NMAT + c0);
        addv8(a, v0); addv8(a, v1); addv8(a, v2); addv8(a, v3);
      }
      for (; t < nn; ++t) {
        addv8(a, *(const uint4*)(Min + (size_t)ip[t] * NMAT + c0));
      }
    }
  }
  // T1 -> LDS. bf16 path: pack both rows into one uint per column
  // (adds <1e-10 to final s; bank-conflict-free random b32 reads in B).
  if (in32) {
#pragma unroll
    for (int cc = 0; cc < 8; ++cc)
      ldsF[c0 + cc] = make_float2(acc[0][cc], acc[1][cc]);
  } else {
    unsigned u[8];
#pragma unroll
    for (int cc = 0; cc < 8; ++cc)
      u[cc] = (unsigned)f2bf(acc[0][cc]) | ((unsigned)f2bf(acc[1][cc]) << 16);
    *(uint4*)&ldsU[c0] = make_uint4(u[0], u[1], u[2], u[3]);
    *(uint4*)&ldsU[c0 + 4] = make_uint4(u[4], u[5], u[6], u[7]);
  }
  __syncthreads();

  // ---- Phase B: column gathers from LDS + epilogue ----
  const float alpha = 0.82f;
  const float oma = 1.0f - alpha;
#pragma unroll
  for (int jj = 0; jj < 8; ++jj) {
    int j = jj * 256 + tid;
    int nn = cnt2[j];
    const unsigned short* bp = idx2T4 + j * 4;
    size_t off0 = (size_t)i0 * NMAT + j;
    size_t off1 = off0 + NMAT;
    // prefetch epilogue operands (latency hides under the gather)
    float e0a, e0b, e1a, e1b;
    if (last) {
      e0a = Ht[off0]; e0b = q[off0];
      e1a = Ht[off1]; e1b = q[off1];
    } else {
      e0a = Q2[off0]; e0b = bf2f(M0base[off0]);
      e1a = Q2[off1]; e1b = bf2f(M0base[off1]);
    }
    float s0 = 0.f, s1 = 0.f;
    int t = 0;
    if (in32) {
      for (; t + 4 <= nn; t += 4) {
        uint2 ga = *(const uint2*)(bp + (size_t)(t >> 2) * GS);
        float2 va = ldsF[ga.x & 0xffff];
        float2 vb = ldsF[ga.x >> 16];
        float2 vc = ldsF[ga.y & 0xffff];
        float2 vd = ldsF[ga.y >> 16];
        s0 += (va.x + vb.x) + (vc.x + vd.x);
        s1 += (va.y + vb.y) + (vc.y + vd.y);
      }
      for (; t < nn; ++t) {
        int k = bp[(size_t)(t >> 2) * GS + (t & 3)];
        float2 v = ldsF[k];
        s0 += v.x; s1 += v.y;
      }
    } else {
      for (; t + 8 <= nn; t += 8) {
        const unsigned short* gp = bp + (size_t)(t >> 2) * GS;
        uint2 ga = *(const uint2*)gp;
        uint2 gb = *(const uint2*)(gp + GS);
        unsigned w0 = ldsU[ga.x & 0xffff], w1 = ldsU[ga.x >> 16];
        unsigned w2 = ldsU[ga.y & 0xffff], w3 = ldsU[ga.y >> 16];
        unsigned w4 = ldsU[gb.x & 0xffff], w5 = ldsU[gb.x >> 16];
        unsigned w6 = ldsU[gb.y & 0xffff], w7 = ldsU[gb.y >> 16];
        s0 += (bflo(w0) + bflo(w1)) + (bflo(w2) + bflo(w3)) +
              (bflo(w4) + bflo(w5)) + (bflo(w6) + bflo(w7));
        s1 += (bfhi(w0) + bfhi(w1)) + (bfhi(w2) + bfhi(w3)) +
              (bfhi(w4) + bfhi(w5)) + (bfhi(w6) + bfhi(w7));
      }
      for (; t + 4 <= nn; t += 4) {
        uint2 ga = *(const uint2*)(bp + (size_t)(t >> 2) * GS);
        unsigned w0 = ldsU[ga.x & 0xffff], w1 = ldsU[ga.x >> 16];
        unsigned w2 = ldsU[ga.y & 0xffff], w3 = ldsU[ga.y >> 16];
        s0 += (bflo(w0) + bflo(w1)) + (bflo(w2) + bflo(w3));
        s1 += (bfhi(w0) + bfhi(w1)) + (bfhi(w2) + bfhi(w3));
      }
      for (; t < nn; ++t) {
        int k = bp[(size_t)(t >> 2) * GS + (t & 3)];
        unsigned w = ldsU[k];
        s0 += bflo(w); s1 += bfhi(w);
      }
    }
    if (last) {
      sout[off0] = oma * e0a + alpha * e0b * s0;
      sout[off1] = oma * e1a + alpha * e1b * s1;
    } else if (out32) {
      MoutF[off0] = fmaf(e0a, s0, e0b);
      MoutF[off1] = fmaf(e1a, s1, e1b);
    } else {
      Mout[off0] = f2bf(fmaf(e0a, s0, e0b));
      Mout[off1] = f2bf(fmaf(e1a, s1, e1b));
    }
  }
}

extern "C" void kernel_launch(void* const* d_in, const int* in_sizes, int n_in,
                              void* d_out, int out_size, void* d_ws,
                              size_t ws_size, hipStream_t stream) {
  const float* A1 = (const float*)d_in[0];
  const float* A2 = (const float*)d_in[1];
  const float* N1 = (const float*)d_in[2];
  const float* N2 = (const float*)d_in[3];
  const float* H = (const float*)d_in[4];
  float* s_out = (float*)d_out;

  char* p = (char*)d_ws;
  auto take = [&](size_t bytes) {
    char* r = p;
    p += (bytes + 255) & ~(size_t)255;
    return r;
  };
  unsigned short* idx1 = (unsigned short*)take((size_t)NMAT * CAP * 2);
  unsigned short* idx2 = (unsigned short*)take((size_t)NMAT * CAP * 2);
  unsigned short* idx2T4 = (unsigned short*)take((size_t)CAP * NMAT * 2);
  int* cnt1 = (int*)take((size_t)NMAT * 4);
  int* cnt2 = (int*)take((size_t)NMAT * 4);
  float* N1n = (float*)take((size_t)NMAT * KATTR * 4);
  float* N2n = (float*)take((size_t)NMAT * KATTR * 4);
  float* C1 = (float*)take((size_t)NMAT * KATTR * 4);
  float* C2 = (float*)take((size_t)NMAT * KATTR * 4);
  float* Ht = (float*)take((size_t)NMAT * NMAT * 4);
  float* q = (float*)take((size_t)NMAT * NMAT * 4);
  float* Q2 = (float*)take((size_t)NMAT * NMAT * 4);
  unsigned short* Mb0 = (unsigned short*)take((size_t)NMAT * NMAT * 2);
  unsigned short* Mb1 = (unsigned short*)take((size_t)NMAT * NMAT * 2);
  unsigned short* M0b = (unsigned short*)take((size_t)NMAT * NMAT * 2);
  float* Mf = (float*)take((size_t)NMAT * NMAT * 4);
  if ((size_t)(p - (char*)d_ws) > ws_size) return;

  k_build<<<NMAT, 256, 0, stream>>>(A1, idx1, (unsigned short*)nullptr, cnt1);
  k_build<<<NMAT, 256, 0, stream>>>(A2, idx2, idx2T4, cnt2);
  k_norm<<<NMAT / 4, 256, 0, stream>>>(N1, N1n);
  k_norm<<<NMAT / 4, 256, 0, stream>>>(N2, N2n);
  k_gatherN<<<NMAT, 64, 0, stream>>>(idx1, cnt1, N1n, C1);
  k_gatherN<<<NMAT, 64, 0, stream>>>(idx2, cnt2, N2n, C2);
  k_transpose<<<dim3(32, 32), 256, 0, stream>>>(H, Ht);
  k_q<<<dim3(32, 32), 256, 0, stream>>>(N1n, C1, N2n, C2, Ht, q, Q2, Mb0,
                                        M0b);
  for (int it = 0; it < NITER; ++it) {
    const unsigned short* Min = (it & 1) ? Mb1 : Mb0;
    unsigned short* Mout = (it & 1) ? Mb0 : Mb1;
    int in32 = (it == NITER - 1) ? 1 : 0;
    int out32 = (it == NITER - 2) ? 1 : 0;
    int last = (it == NITER - 1) ? 1 : 0;
    k_iter<<<NMAT / 2, 256, 0, stream>>>(idx1, cnt1, idx2T4, cnt2, Min, Mf,
                                         Q2, M0b, q, Ht, Mout, Mf, s_out,
                                         in32, out32, last);
  }
}

// Round 2
// 426.086 us; speedup vs baseline: 1.3015x; 1.3015x over previous
//
#include <hip/hip_runtime.h>

#define NMAT 2048
#define KATTR 64
#define CAP 128
#define NITER 10
#define SENT_A 2048  // Phase A sentinel: extra zeroed row of M buffers
#define SENT_B 2057  // Phase B sentinel: swz(2057)=8232, outside real swz image

typedef unsigned short ushort4v __attribute__((ext_vector_type(4)));

__device__ __forceinline__ unsigned short f2bf(float f) {
  unsigned u = __float_as_uint(f);
  return (unsigned short)((u + 0x7fff + ((u >> 16) & 1)) >> 16);
}
__device__ __forceinline__ float bf2f(unsigned short b) {
  return __uint_as_float((unsigned)b << 16);
}
__device__ __forceinline__ float bflo(unsigned v) {
  return __uint_as_float(v << 16);
}
__device__ __forceinline__ float bfhi(unsigned v) {
  return __uint_as_float(v & 0xffff0000u);
}
// swizzled LDS dword index (proven v3): real cols map to [0, 8219+3];
// SENT_B=2057 maps to 8232..8235 (zeroed, disjoint from all real cols).
__device__ __forceinline__ int swz(int c) { return 4 * c + (((c >> 3) & 7) << 2); }

// --------------------------------------------------------------------------
// Build padded adjacency (ELL); sentinel-fill unused slots up to CAP so the
// gather loops never need scalar tails.
// idxT4 (Phase B): 4 edges/group at idxT4[g*NMAT*4 + r*4 + (p&3)].
// --------------------------------------------------------------------------
__global__ __launch_bounds__(256) void k_build(
    const float* __restrict__ A, unsigned short* __restrict__ idx,
    unsigned short* __restrict__ idxT4, int* __restrict__ cnt) {
  __shared__ int lcnt;
  int r = blockIdx.x;
  if (threadIdx.x == 0) lcnt = 0;
  __syncthreads();
  const float* row = A + (size_t)r * NMAT;
  for (int c = threadIdx.x; c < NMAT; c += 256) {
    if (row[c] != 0.0f) {
      int p = atomicAdd(&lcnt, 1);
      if (p < CAP) {
        idx[r * CAP + p] = (unsigned short)c;
        if (idxT4)
          idxT4[(size_t)(p >> 2) * (NMAT * 4) + r * 4 + (p & 3)] =
              (unsigned short)c;
      }
    }
  }
  __syncthreads();
  int n = lcnt < CAP ? lcnt : CAP;
  for (int p = n + threadIdx.x; p < CAP; p += 256) {
    idx[r * CAP + p] = (unsigned short)SENT_A;
    if (idxT4)
      idxT4[(size_t)(p >> 2) * (NMAT * 4) + r * 4 + (p & 3)] =
          (unsigned short)SENT_B;
  }
  if (threadIdx.x == 0) cnt[r] = n;
}

__global__ __launch_bounds__(256) void k_norm(const float* __restrict__ Nin,
                                              float* __restrict__ Nout) {
  int row = blockIdx.x * 4 + (threadIdx.x >> 6);
  int lane = threadIdx.x & 63;
  float v = Nin[(size_t)row * KATTR + lane];
  float ss = v * v;
#pragma unroll
  for (int o = 32; o > 0; o >>= 1) ss += __shfl_xor(ss, o);
  float nrm = sqrtf(ss);
  Nout[(size_t)row * KATTR + lane] = (nrm > 0.f) ? v / nrm : 0.f;
}

__global__ void k_gatherN(const unsigned short* __restrict__ idx,
                          const int* __restrict__ cnt,
                          const float* __restrict__ Nn,
                          float* __restrict__ C) {
  int i = blockIdx.x;
  int lane = threadIdx.x;  // blockDim = 64
  int nn = cnt[i];
  const unsigned short* ip = idx + i * CAP;
  float acc = 0.f;
  for (int t = 0; t < nn; ++t) {
    int k = ip[t];
    acc += Nn[(size_t)k * KATTR + lane];
  }
  C[(size_t)i * KATTR + lane] = acc;
}

__global__ __launch_bounds__(256) void k_transpose(const float* __restrict__ H,
                                                   float* __restrict__ Ht) {
  __shared__ float tile[64][65];
  int j0 = blockIdx.x * 64;
  int i0 = blockIdx.y * 64;
  int c = threadIdx.x & 63;
  int r0 = threadIdx.x >> 6;
  for (int r = r0; r < 64; r += 4)
    tile[r][c] = H[(size_t)(j0 + r) * NMAT + i0 + c];
  __syncthreads();
  for (int r = r0; r < 64; r += 4)
    Ht[(size_t)(i0 + r) * NMAT + j0 + c] = tile[c][r];
}

// Zero the sentinel row (row 2048) of the gather buffers, once.
__global__ __launch_bounds__(1024) void k_zrow(unsigned short* __restrict__ Mb0,
                                               unsigned short* __restrict__ Mb1,
                                               float* __restrict__ Mf) {
  size_t Z = (size_t)NMAT * NMAT;
  for (int o = threadIdx.x; o < NMAT; o += 1024) {
    Mb0[Z + o] = 0;
    Mb1[Z + o] = 0;
    Mf[Z + o] = 0.f;
  }
}

// --------------------------------------------------------------------------
// q = Nm>0&dm>0 ? Nm*rsqrt(Nm*dm) : 0.
// Outputs: M0gather = bf16(q*Ht), q (fp32, last iter),
// QM = pack(bf16(alpha*q^2) | bf16((1-a)*q*Ht) << 16)  -- one 4B epilogue
// word per element instead of fp32 Q2 + bf16 M0base (saves 8 MB/iter fetch).
// --------------------------------------------------------------------------
__global__ __launch_bounds__(256) void k_q(
    const float* __restrict__ N1n, const float* __restrict__ C1,
    const float* __restrict__ N2n, const float* __restrict__ C2,
    const float* __restrict__ Ht, float* __restrict__ q,
    unsigned* __restrict__ QM, unsigned short* __restrict__ M) {
  __shared__ float sA[64][68];
  __shared__ float sB[64][68];
  int i0 = blockIdx.y * 64, j0 = blockIdx.x * 64;
  int c = threadIdx.x & 63, r0 = threadIdx.x >> 6;
  int tx = threadIdx.x & 15, ty = threadIdx.x >> 4;
  const float alpha = 0.82f;

  float nmv[4][4] = {};
  float dmv[4][4] = {};

  for (int r = r0; r < 64; r += 4) {
    sA[c][r] = N1n[(size_t)(i0 + r) * KATTR + c];
    sB[c][r] = N2n[(size_t)(j0 + r) * KATTR + c];
  }
  __syncthreads();
#pragma unroll 4
  for (int k = 0; k < 64; ++k) {
    float4 a = *(const float4*)&sA[k][ty * 4];
    float4 b = *(const float4*)&sB[k][tx * 4];
    float av[4] = {a.x, a.y, a.z, a.w};
    float bv[4] = {b.x, b.y, b.z, b.w};
#pragma unroll
    for (int ii = 0; ii < 4; ++ii)
#pragma unroll
      for (int jj = 0; jj < 4; ++jj)
        nmv[ii][jj] = fmaf(av[ii], bv[jj], nmv[ii][jj]);
  }
  __syncthreads();
  for (int r = r0; r < 64; r += 4) {
    sA[c][r] = C1[(size_t)(i0 + r) * KATTR + c];
    sB[c][r] = C2[(size_t)(j0 + r) * KATTR + c];
  }
  __syncthreads();
#pragma unroll 4
  for (int k = 0; k < 64; ++k) {
    float4 a = *(const float4*)&sA[k][ty * 4];
    float4 b = *(const float4*)&sB[k][tx * 4];
    float av[4] = {a.x, a.y, a.z, a.w};
    float bv[4] = {b.x, b.y, b.z, b.w};
#pragma unroll
    for (int ii = 0; ii < 4; ++ii)
#pragma unroll
      for (int jj = 0; jj < 4; ++jj)
        dmv[ii][jj] = fmaf(av[ii], bv[jj], dmv[ii][jj]);
  }

#pragma unroll
  for (int ii = 0; ii < 4; ++ii) {
    int i = i0 + ty * 4 + ii;
    size_t base = (size_t)i * NMAT + j0 + tx * 4;
    float4 hv = *(const float4*)&Ht[base];
    float hvv[4] = {hv.x, hv.y, hv.z, hv.w};
    float qv[4];
    unsigned qmv[4];
    ushort4v mv;
#pragma unroll
    for (int jj = 0; jj < 4; ++jj) {
      float nmx = nmv[ii][jj];
      float D = nmx * dmv[ii][jj];
      float qq = (D > 0.f) ? nmx * rsqrtf(D) : 0.f;
      qv[jj] = qq;
      float m0 = qq * hvv[jj];
      mv[jj] = f2bf(m0);
      qmv[jj] = (unsigned)f2bf(alpha * qq * qq) |
                ((unsigned)f2bf((1.0f - alpha) * m0) << 16);
    }
    *(float4*)&q[base] = make_float4(qv[0], qv[1], qv[2], qv[3]);
    *(uint4*)&QM[base] = make_uint4(qmv[0], qmv[1], qmv[2], qmv[3]);
    *(ushort4v*)&M[base] = mv;
  }
}

// --------------------------------------------------------------------------
// One full iteration, fused (v5 = v3 structure + latency fixes).
// Grid 512 x 1024 (16 waves/block, 2 blocks/CU = 32 waves/CU).
// v4 post-mortem: halving waves regressed (latency-bound at ~25% pipe util),
// so keep v3's parallelism and instead remove serialized latency:
//  - sentinel-padded ELL => no scalar tails (each was a ~300cy round trip)
//  - whole-row index preload (2x uint4, wave-uniform) => 16 data loads in
//    flight with no dependent index fetch in between
//  - packed idx2T4 groups (v4's one good idea) + packed QM epilogue word
// --------------------------------------------------------------------------
__global__ __launch_bounds__(1024, 8) void k_iter(
    const unsigned short* __restrict__ idx1, const int* __restrict__ cnt1,
    const unsigned short* __restrict__ idx2T4, const int* __restrict__ cnt2,
    const unsigned short* __restrict__ Min, const float* __restrict__ MinF,
    const unsigned* __restrict__ QM, const float* __restrict__ q,
    const float* __restrict__ Ht, unsigned short* __restrict__ Mout,
    float* __restrict__ MoutF, float* __restrict__ sout, int in32, int out32,
    int last) {
  __shared__ float lds[4 * NMAT + 64];
  const int GS = NMAT * 4;  // idx2T4 group stride (ushorts)
  int i0 = blockIdx.x * 4;
  int tid = threadIdx.x;  // 0..1023
  int c0 = tid * 2;       // this thread's 2 columns

  if (tid == 0) *(float4*)&lds[swz(SENT_B)] = make_float4(0.f, 0.f, 0.f, 0.f);

  // ---- Phase A: row gathers ----
  float acc[4][2];
#pragma unroll
  for (int r = 0; r < 4; ++r) {
    int nn = cnt1[i0 + r];
    const unsigned short* ip = idx1 + (i0 + r) * CAP;
    // whole-row index preload (sentinel-padded, always valid)
    uint4 pA = *(const uint4*)(ip);
    uint4 pB = *(const uint4*)(ip + 8);
    uint4 pC = *(const uint4*)(ip + 16);
    uint4 pD = *(const uint4*)(ip + 24);
    float a0 = 0.f, a1 = 0.f;
    if (in32) {
      const float* Bf = MinF + c0;
      auto g8f = [&](uint4 pk, float2* w) {
        w[0] = *(const float2*)(Bf + (size_t)(pk.x & 0xffff) * NMAT);
        w[1] = *(const float2*)(Bf + (size_t)(pk.x >> 16) * NMAT);
        w[2] = *(const float2*)(Bf + (size_t)(pk.y & 0xffff) * NMAT);
        w[3] = *(const float2*)(Bf + (size_t)(pk.y >> 16) * NMAT);
        w[4] = *(const float2*)(Bf + (size_t)(pk.z & 0xffff) * NMAT);
        w[5] = *(const float2*)(Bf + (size_t)(pk.z >> 16) * NMAT);
        w[6] = *(const float2*)(Bf + (size_t)(pk.w & 0xffff) * NMAT);
        w[7] = *(const float2*)(Bf + (size_t)(pk.w >> 16) * NMAT);
      };
      float2 w[16];
      g8f(pA, w);
      g8f(pB, w + 8);
#pragma unroll
      for (int e = 0; e < 16; ++e) {
        a0 += w[e].x;
        a1 += w[e].y;
      }
      if (nn > 16) {
        float2 w2[16];
        g8f(pC, w2);
        g8f(pD, w2 + 8);
#pragma unroll
        for (int e = 0; e < 16; ++e) {
          a0 += w2[e].x;
          a1 += w2[e].y;
        }
      }
      for (int t = 32; t < nn; t += 8) {
        uint4 pk = *(const uint4*)(ip + t);
        float2 w3[8];
        g8f(pk, w3);
#pragma unroll
        for (int e = 0; e < 8; ++e) {
          a0 += w3[e].x;
          a1 += w3[e].y;
        }
      }
    } else {
      const unsigned short* Bb = Min + c0;
      auto g8 = [&](uint4 pk, unsigned* w) {
        w[0] = *(const unsigned*)(Bb + (size_t)(pk.x & 0xffff) * NMAT);
        w[1] = *(const unsigned*)(Bb + (size_t)(pk.x >> 16) * NMAT);
        w[2] = *(const unsigned*)(Bb + (size_t)(pk.y & 0xffff) * NMAT);
        w[3] = *(const unsigned*)(Bb + (size_t)(pk.y >> 16) * NMAT);
        w[4] = *(const unsigned*)(Bb + (size_t)(pk.z & 0xffff) * NMAT);
        w[5] = *(const unsigned*)(Bb + (size_t)(pk.z >> 16) * NMAT);
        w[6] = *(const unsigned*)(Bb + (size_t)(pk.w & 0xffff) * NMAT);
        w[7] = *(const unsigned*)(Bb + (size_t)(pk.w >> 16) * NMAT);
      };
      unsigned w[16];
      g8(pA, w);
      g8(pB, w + 8);
      bool more = nn > 16;
      unsigned w2[16];
      if (more) {
        g8(pC, w2);
        g8(pD, w2 + 8);
      }
#pragma unroll
      for (int e = 0; e < 16; ++e) {
        a0 += bflo(w[e]);
        a1 += bfhi(w[e]);
      }
      if (more) {
#pragma unroll
        for (int e = 0; e < 16; ++e) {
          a0 += bflo(w2[e]);
          a1 += bfhi(w2[e]);
        }
      }
      for (int t = 32; t < nn; t += 8) {
        uint4 pk = *(const uint4*)(ip + t);
        unsigned w3[8];
        g8(pk, w3);
#pragma unroll
        for (int e = 0; e < 8; ++e) {
          a0 += bflo(w3[e]);
          a1 += bfhi(w3[e]);
        }
      }
    }
    acc[r][0] = a0;
    acc[r][1] = a1;
  }
  *(float4*)&lds[swz(c0)] =
      make_float4(acc[0][0], acc[1][0], acc[2][0], acc[3][0]);
  *(float4*)&lds[swz(c0 + 1)] =
      make_float4(acc[0][1], acc[1][1], acc[2][1], acc[3][1]);
  __syncthreads();

  // ---- Phase B: column gathers from LDS + epilogue ----
  const float alpha = 0.82f;
  const float oma = 1.0f - alpha;
#pragma unroll
  for (int jj = 0; jj < 2; ++jj) {
    int j = jj * 1024 + tid;
    int nn = cnt2[j];
    const unsigned short* bp = idx2T4 + j * 4;
    size_t off0 = (size_t)i0 * NMAT + j;
    // prefetch epilogue operands (hide under gather)
    unsigned wq0 = 0, wq1 = 0, wq2 = 0, wq3 = 0;
    if (!last) {
      wq0 = QM[off0];
      wq1 = QM[off0 + NMAT];
      wq2 = QM[off0 + 2 * NMAT];
      wq3 = QM[off0 + 3 * NMAT];
    }
    // first 16 edges unconditionally (sentinel slots are zeroed broadcast)
    uint2 g0 = *(const uint2*)(bp);
    uint2 g1 = *(const uint2*)(bp + GS);
    uint2 g2 = *(const uint2*)(bp + 2 * GS);
    uint2 g3 = *(const uint2*)(bp + 3 * GS);
    float s0 = 0.f, s1 = 0.f, s2 = 0.f, s3 = 0.f;
    float u0 = 0.f, u1 = 0.f, u2 = 0.f, u3 = 0.f;
    {
      float4 va = *(const float4*)&lds[swz(g0.x & 0xffff)];
      float4 vb = *(const float4*)&lds[swz(g0.x >> 16)];
      float4 vc = *(const float4*)&lds[swz(g0.y & 0xffff)];
      float4 vd = *(const float4*)&lds[swz(g0.y >> 16)];
      float4 ve = *(const float4*)&lds[swz(g1.x & 0xffff)];
      float4 vf = *(const float4*)&lds[swz(g1.x >> 16)];
      float4 vg = *(const float4*)&lds[swz(g1.y & 0xffff)];
      float4 vh = *(const float4*)&lds[swz(g1.y >> 16)];
      s0 += (va.x + vb.x) + (vc.x + vd.x);
      s1 += (va.y + vb.y) + (vc.y + vd.y);
      s2 += (va.z + vb.z) + (vc.z + vd.z);
      s3 += (va.w + vb.w) + (vc.w + vd.w);
      u0 += (ve.x + vf.x) + (vg.x + vh.x);
      u1 += (ve.y + vf.y) + (vg.y + vh.y);
      u2 += (ve.z + vf.z) + (vg.z + vh.z);
      u3 += (ve.w + vf.w) + (vg.w + vh.w);
    }
    {
      float4 va = *(const float4*)&lds[swz(g2.x & 0xffff)];
      float4 vb = *(const float4*)&lds[swz(g2.x >> 16)];
      float4 vc = *(const float4*)&lds[swz(g2.y & 0xffff)];
      float4 vd = *(const float4*)&lds[swz(g2.y >> 16)];
      float4 ve = *(const float4*)&lds[swz(g3.x & 0xffff)];
      float4 vf = *(const float4*)&lds[swz(g3.x >> 16)];
      float4 vg = *(const float4*)&lds[swz(g3.y & 0xffff)];
      float4 vh = *(const float4*)&lds[swz(g3.y >> 16)];
      s0 += (va.x + vb.x) + (vc.x + vd.x);
      s1 += (va.y + vb.y) + (vc.y + vd.y);
      s2 += (va.z + vb.z) + (vc.z + vd.z);
      s3 += (va.w + vb.w) + (vc.w + vd.w);
      u0 += (ve.x + vf.x) + (vg.x + vh.x);
      u1 += (ve.y + vf.y) + (vg.y + vh.y);
      u2 += (ve.z + vf.z) + (vg.z + vh.z);
      u3 += (ve.w + vf.w) + (vg.w + vh.w);
    }
    for (int t = 16; t < nn; t += 8) {
      uint2 ga = *(const uint2*)(bp + (size_t)(t >> 2) * GS);
      uint2 gb = *(const uint2*)(bp + (size_t)((t >> 2) + 1) * GS);
      float4 va = *(const float4*)&lds[swz(ga.x & 0xffff)];
      float4 vb = *(const float4*)&lds[swz(ga.x >> 16)];
      float4 vc = *(const float4*)&lds[swz(ga.y & 0xffff)];
      float4 vd = *(const float4*)&lds[swz(ga.y >> 16)];
      float4 ve = *(const float4*)&lds[swz(gb.x & 0xffff)];
      float4 vf = *(const float4*)&lds[swz(gb.x >> 16)];
      float4 vg = *(const float4*)&lds[swz(gb.y & 0xffff)];
      float4 vh = *(const float4*)&lds[swz(gb.y >> 16)];
      s0 += (va.x + vb.x) + (vc.x + vd.x);
      s1 += (va.y + vb.y) + (vc.y + vd.y);
      s2 += (va.z + vb.z) + (vc.z + vd.z);
      s3 += (va.w + vb.w) + (vc.w + vd.w);
      u0 += (ve.x + vf.x) + (vg.x + vh.x);
      u1 += (ve.y + vf.y) + (vg.y + vh.y);
      u2 += (ve.z + vf.z) + (vg.z + vh.z);
      u3 += (ve.w + vf.w) + (vg.w + vh.w);
    }
    float sa[4] = {s0 + u0, s1 + u1, s2 + u2, s3 + u3};
    if (last) {
#pragma unroll
      for (int r = 0; r < 4; ++r) {
        size_t off = off0 + (size_t)r * NMAT;
        sout[off] = oma * Ht[off] + alpha * q[off] * sa[r];
      }
    } else if (out32) {
      MoutF[off0] = fmaf(bflo(wq0), sa[0], bfhi(wq0));
      MoutF[off0 + NMAT] = fmaf(bflo(wq1), sa[1], bfhi(wq1));
      MoutF[off0 + 2 * NMAT] = fmaf(bflo(wq2), sa[2], bfhi(wq2));
      MoutF[off0 + 3 * NMAT] = fmaf(bflo(wq3), sa[3], bfhi(wq3));
    } else {
      Mout[off0] = f2bf(fmaf(bflo(wq0), sa[0], bfhi(wq0)));
      Mout[off0 + NMAT] = f2bf(fmaf(bflo(wq1), sa[1], bfhi(wq1)));
      Mout[off0 + 2 * NMAT] = f2bf(fmaf(bflo(wq2), sa[2], bfhi(wq2)));
      Mout[off0 + 3 * NMAT] = f2bf(fmaf(bflo(wq3), sa[3], bfhi(wq3)));
    }
  }
}

extern "C" void kernel_launch(void* const* d_in, const int* in_sizes, int n_in,
                              void* d_out, int out_size, void* d_ws,
                              size_t ws_size, hipStream_t stream) {
  const float* A1 = (const float*)d_in[0];
  const float* A2 = (const float*)d_in[1];
  const float* N1 = (const float*)d_in[2];
  const float* N2 = (const float*)d_in[3];
  const float* H = (const float*)d_in[4];
  float* s_out = (float*)d_out;

  char* p = (char*)d_ws;
  auto take = [&](size_t bytes) {
    char* r = p;
    p += (bytes + 255) & ~(size_t)255;
    return r;
  };
  unsigned short* idx1 = (unsigned short*)take((size_t)NMAT * CAP * 2);
  unsigned short* idx2 = (unsigned short*)take((size_t)NMAT * CAP * 2);
  unsigned short* idx2T4 = (unsigned short*)take((size_t)CAP * NMAT * 2);
  int* cnt1 = (int*)take((size_t)NMAT * 4);
  int* cnt2 = (int*)take((size_t)NMAT * 4);
  float* N1n = (float*)take((size_t)NMAT * KATTR * 4);
  float* N2n = (float*)take((size_t)NMAT * KATTR * 4);
  float* C1 = (float*)take((size_t)NMAT * KATTR * 4);
  float* C2 = (float*)take((size_t)NMAT * KATTR * 4);
  float* Ht = (float*)take((size_t)NMAT * NMAT * 4);
  float* q = (float*)take((size_t)NMAT * NMAT * 4);
  unsigned* QM = (unsigned*)take((size_t)NMAT * NMAT * 4);
  unsigned short* Mb0 = (unsigned short*)take((size_t)(NMAT + 1) * NMAT * 2);
  unsigned short* Mb1 = (unsigned short*)take((size_t)(NMAT + 1) * NMAT * 2);
  float* Mf = (float*)take((size_t)(NMAT + 1) * NMAT * 4);
  if ((size_t)(p - (char*)d_ws) > ws_size) return;

  k_build<<<NMAT, 256, 0, stream>>>(A1, idx1, (unsigned short*)nullptr, cnt1);
  k_build<<<NMAT, 256, 0, stream>>>(A2, idx2, idx2T4, cnt2);
  k_norm<<<NMAT / 4, 256, 0, stream>>>(N1, N1n);
  k_norm<<<NMAT / 4, 256, 0, stream>>>(N2, N2n);
  k_gatherN<<<NMAT, 64, 0, stream>>>(idx1, cnt1, N1n, C1);
  k_gatherN<<<NMAT, 64, 0, stream>>>(idx2, cnt2, N2n, C2);
  k_transpose<<<dim3(32, 32), 256, 0, stream>>>(H, Ht);
  k_q<<<dim3(32, 32), 256, 0, stream>>>(N1n, C1, N2n, C2, Ht, q, QM, Mb0);
  k_zrow<<<1, 1024, 0, stream>>>(Mb0, Mb1, Mf);
  for (int it = 0; it < NITER; ++it) {
    const unsigned short* Min = (it & 1) ? Mb1 : Mb0;
    unsigned short* Mout = (it & 1) ? Mb0 : Mb1;
    int in32 = (it == NITER - 1) ? 1 : 0;
    int out32 = (it == NITER - 2) ? 1 : 0;
    int last = (it == NITER - 1) ? 1 : 0;
    k_iter<<<NMAT / 4, 1024, 0, stream>>>(idx1, cnt1, idx2T4, cnt2, Min, Mf,
                                          QM, q, Ht, Mout, Mf, s_out, in32,
                                          out32, last);
  }
}